// Round 9
// baseline (276.317 us; speedup 1.0000x reference)
//
#include <hip/hip_runtime.h>
#include <hip/hip_bf16.h>
#include <stdint.h>

// Causal MHA. B=4 S=2048 D=1024 H=16 Dh=64.
// fp32 I/O, bf16 MFMA internals. Softmax in exp2-space (scale baked into Q).
// flash: full K/V LDS double-buffer, 1 barrier/iter (prefetch covered by compute).
// gemm: XCD-swizzled block mapping for L2-local A-slabs.
#define DMODEL 1024
#define NH 16
#define DH 64
#define BATCH 4
#define SEQ 2048

#if __has_builtin(__builtin_amdgcn_exp2f)
#define EXP2F(x) __builtin_amdgcn_exp2f(x)
#else
#define EXP2F(x) exp2f(x)
#endif

typedef __attribute__((ext_vector_type(8))) short short8;   // 8 bf16 = 4 VGPR
typedef __attribute__((ext_vector_type(4))) float f32x4;
typedef __attribute__((ext_vector_type(4))) ushort ushort4v;

__device__ __forceinline__ ushort f2bf(float f) {
    union { float f; unsigned u; } v; v.f = f;
    unsigned r = v.u + 0x7fffu + ((v.u >> 16) & 1u);
    return (ushort)(r >> 16);
}

#define GLL(gp, lp) __builtin_amdgcn_global_load_lds( \
    (const __attribute__((address_space(1))) void*)(gp), \
    (__attribute__((address_space(3))) void*)(lp), 16, 0, 0)

// ---- prep: z<4 -> weight transpose+cvt (64x64 tiles); z==4 -> x fp32->bf16 ----
__global__ __launch_bounds__(256) void prep(
    const float* __restrict__ x,
    const float* __restrict__ wq, const float* __restrict__ wk,
    const float* __restrict__ wv, const float* __restrict__ wo,
    ushort* __restrict__ xbf,
    ushort* __restrict__ dq, ushort* __restrict__ dk,
    ushort* __restrict__ dv, ushort* __restrict__ dwo) {
    const int z = blockIdx.z;
    if (z == 4) {                          // convert x: 256 blocks x 32768 elems
        size_t base = (size_t)(blockIdx.y * 16 + blockIdx.x) * 32768 +
                      (size_t)threadIdx.x * 8;
        #pragma unroll 1
        for (int t = 0; t < 16; ++t, base += 2048) {
            float4 a = *(const float4*)(x + base);
            float4 c = *(const float4*)(x + base + 4);
            short8 r;
            r[0] = (short)f2bf(a.x); r[1] = (short)f2bf(a.y);
            r[2] = (short)f2bf(a.z); r[3] = (short)f2bf(a.w);
            r[4] = (short)f2bf(c.x); r[5] = (short)f2bf(c.y);
            r[6] = (short)f2bf(c.z); r[7] = (short)f2bf(c.w);
            *(short8*)(xbf + base) = r;
        }
        return;
    }
    __shared__ ushort tile[64][65];
    const float* src = (z == 0) ? wq : (z == 1) ? wk : (z == 2) ? wv : wo;
    ushort* dst = (z == 0) ? dq : (z == 1) ? dk : (z == 2) ? dv : dwo;
    const int bx = blockIdx.x * 64, by = blockIdx.y * 64;
    const int tx = threadIdx.x & 63, ty = threadIdx.x >> 6;
    #pragma unroll
    for (int i = 0; i < 64; i += 4)
        tile[ty + i][tx] = f2bf(src[(size_t)(by + ty + i) * DMODEL + bx + tx]);
    __syncthreads();
    #pragma unroll
    for (int i = 0; i < 64; i += 4)
        dst[(size_t)(bx + ty + i) * DMODEL + by + tx] = tile[tx][ty + i];
}

// ---------------- GEMM C = A[M,1024](bf16) * Bt[N,1024](bf16)^T -------------
// XCD swizzle: L&7 -> contiguous 8-m-tile slab per XCD (A slab 2MB fits L2).
// MODE 0: N=3072 -> q/k [B,H,S,Dh], v [B,H,Dh,S] via LDS-transpose epilogue.
// MODE 1: N=1024 -> fp32 out + bias direct.
template <int MODE>
__global__ __launch_bounds__(256) void gemm_bt(
    const ushort* __restrict__ A, const ushort* __restrict__ Bt,
    const float* __restrict__ b0, const float* __restrict__ b1,
    const float* __restrict__ b2,
    void* __restrict__ o0v, void* __restrict__ o1v, void* __restrict__ o2v) {
    __shared__ __align__(16) ushort smem[8192];  // As [0,4096) Bs [4096,8192)
    const int lane = threadIdx.x & 63;
    const int wv   = threadIdx.x >> 6;
    constexpr int NTILES = (MODE == 0) ? 24 : 8;
    const int L   = blockIdx.y * NTILES + blockIdx.x;
    const int xcd = L & 7;
    const int idx = L >> 3;
    const int mBase = (xcd * 8 + idx / NTILES) * 128;
    const int nBase = (idx % NTILES) * 128;
    const int wm = (wv >> 1) * 64;
    const int wn = (wv & 1) * 64;

    f32x4 acc[4][4];
    #pragma unroll
    for (int i = 0; i < 4; ++i)
        #pragma unroll
        for (int j = 0; j < 4; ++j) acc[i][j] = (f32x4){0.f, 0.f, 0.f, 0.f};

    const int lrow = lane >> 2;
    const int lcol = (lane & 3) * 8;
    const int frow = lane & 15;
    const int fcol = (lane >> 4) * 8;

    for (int k0 = 0; k0 < DMODEL; k0 += 32) {
        #pragma unroll
        for (int i = 0; i < 2; ++i) {
            const int c = wv * 2 + i;
            GLL(A + (size_t)(mBase + c * 16 + lrow) * DMODEL + k0 + lcol, &smem[c * 512]);
            GLL(Bt + (size_t)(nBase + c * 16 + lrow) * DMODEL + k0 + lcol,
                &smem[4096 + c * 512]);
        }
        __syncthreads();
        short8 af[4], bfr[4];
        #pragma unroll
        for (int t = 0; t < 4; ++t)
            af[t] = *(const short8*)&smem[(wm + t * 16 + frow) * 32 + fcol];
        #pragma unroll
        for (int t = 0; t < 4; ++t)
            bfr[t] = *(const short8*)&smem[4096 + (wn + t * 16 + frow) * 32 + fcol];
        #pragma unroll
        for (int i = 0; i < 4; ++i)
            #pragma unroll
            for (int j = 0; j < 4; ++j)
                acc[i][j] = __builtin_amdgcn_mfma_f32_16x16x32_bf16(af[i], bfr[j],
                                                                   acc[i][j], 0, 0, 0);
        __syncthreads();
    }

    const int orow = (lane >> 4) * 4;  // C: row=(lane>>4)*4+r, col=lane&15
    const int ocol = lane & 15;

    if (MODE == 1) {
        #pragma unroll
        for (int i = 0; i < 4; ++i)
            #pragma unroll
            for (int j = 0; j < 4; ++j)
                #pragma unroll
                for (int r = 0; r < 4; ++r) {
                    const int m = mBase + wm + i * 16 + orow + r;
                    const int n = nBase + wn + j * 16 + ocol;
                    ((float*)o0v)[(size_t)m * DMODEL + n] = acc[i][j][r] + b0[n];
                }
        return;
    }

    // ---- MODE 0 epilogue: LDS transpose -> b128 coalesced stores ----
    ushort* sw = &smem[wv * 2048];
    const int mat = nBase >> 10;
    const int nb0 = (nBase & 1023) + wn;
    const int hb  = nb0 >> 6;
    const float* bp = (mat == 0) ? b0 : ((mat == 1) ? b1 : b2);
    float bj[4];
    #pragma unroll
    for (int j = 0; j < 4; ++j) bj[j] = bp[nb0 + j * 16 + ocol];
    const int bbq = (mBase + wm) >> 11;
    const int s0w = (mBase + wm) & 2047;
    const float qscale = (mat == 0) ? 0.1803368801f : 1.0f;  // 0.125*log2(e)

    if (mat < 2) {                             // Q/K -> [B,H,S,Dh]
        ushort* obase = (ushort*)((mat == 0) ? o0v : o1v) +
                        ((size_t)(bbq * NH + hb) * SEQ + s0w) * DH;
        const int row = lane >> 2, cc = lane & 3;
        #pragma unroll
        for (int i = 0; i < 4; ++i) {
            #pragma unroll
            for (int j = 0; j < 4; ++j)
                #pragma unroll
                for (int r = 0; r < 4; ++r)
                    sw[(orow + r) * 72 + j * 16 + ocol] =
                        f2bf((acc[i][j][r] + bj[j]) * qscale);
            asm volatile("s_waitcnt lgkmcnt(0)" ::: "memory");
            #pragma unroll
            for (int p = 0; p < 2; ++p) {
                short8 v8 = *(const short8*)&sw[row * 72 + cc * 8 + p * 32];
                *(short8*)&obase[(size_t)(i * 16 + row) * DH + cc * 8 + p * 32] = v8;
            }
            asm volatile("s_waitcnt lgkmcnt(0)" ::: "memory");
        }
    } else {                                   // V -> [B,H,Dh,S]
        ushort* op = (ushort*)o2v;
        const int rowd = lane >> 2, sc = lane & 3;
        #pragma unroll
        for (int j = 0; j < 4; ++j) {
            #pragma unroll
            for (int i = 0; i < 4; ++i)
                #pragma unroll
                for (int r = 0; r < 4; ++r)
                    sw[ocol * 72 + i * 16 + orow + r] = f2bf(acc[i][j][r] + bj[j]);
            asm volatile("s_waitcnt lgkmcnt(0)" ::: "memory");
            ushort* vbase = op + ((size_t)(bbq * NH + hb) * DH + j * 16 + rowd) * SEQ + s0w;
            #pragma unroll
            for (int p = 0; p < 2; ++p) {
                short8 v8 = *(const short8*)&sw[rowd * 72 + sc * 8 + p * 32];
                *(short8*)&vbase[sc * 8 + p * 32] = v8;
            }
            asm volatile("s_waitcnt lgkmcnt(0)" ::: "memory");
        }
    }
}

// ---------------- flash attention: dbuf K/V, 1 barrier/iter -----------------
// Block = 4 waves = 64 q rows; pairs (J, 31-J) -> uniform work; 4 blocks/CU.
// Prefetch tile it+1 at iter head; barrier at iter end drains it after the
// whole compute phase has covered the latency. PV in two 32-key passes so the
// per-wave P-buffer is 16x32 (PSTR2=40 pad, ~2-way conflicts) -> LDS 37.9KB.
#define PSTR2 40
__global__ __launch_bounds__(256, 4) void flash_attn(
    const ushort* __restrict__ Q, const ushort* __restrict__ K,
    const ushort* __restrict__ Vt, ushort* __restrict__ ctx) {
    __shared__ __align__(16) ushort Ks[2][4096];        // 2 x 8KB
    __shared__ __align__(16) ushort Vs[2][4096];        // 2 x 8KB
    __shared__ __align__(16) ushort plds[4][16 * PSTR2];
    const int lane = threadIdx.x & 63;
    const int wv   = threadIdx.x >> 6;
    const int bh   = blockIdx.x & 63;
    const int Jp   = blockIdx.x >> 6;
    const int bb = bh >> 4, h = bh & 15;

    const ushort* Qb = Q + (size_t)bh * SEQ * DH;
    const ushort* Kb = K + (size_t)bh * SEQ * DH;
    const ushort* Vb = Vt + (size_t)bh * DH * SEQ;

    const int frow = lane & 15;
    const int fq   = lane >> 4;
    const int r7s  = lane >> 3;
    const int csw  = (lane & 7) ^ r7s;

    short8 ones;
    #pragma unroll
    for (int i = 0; i < 8; ++i) ones[i] = (short)0x3F80;

    #pragma unroll 1
    for (int half = 0; half < 2; ++half) {
        const int Je = half ? (31 - Jp) : Jp;
        const int q0 = Je * 64 + wv * 16;
        const int qmax = q0 + 15;
        const int qrow = q0 + frow;

        short8 qf[2];
        #pragma unroll
        for (int ks = 0; ks < 2; ++ks)
            qf[ks] = *(const short8*)&Qb[(size_t)(q0 + frow) * DH + ks * 32 + fq * 8];

        f32x4 o[4], lacc;
        #pragma unroll
        for (int t = 0; t < 4; ++t) o[t] = (f32x4){0.f, 0.f, 0.f, 0.f};
        lacc = (f32x4){0.f, 0.f, 0.f, 0.f};

        // preload tile 0 -> buffer 0
        #pragma unroll
        for (int i = 0; i < 2; ++i) {
            const int c = wv * 2 + i;
            GLL(Kb + (size_t)(c * 8 + r7s) * DH + csw * 8, &Ks[0][c * 512]);
            GLL(Vb + (size_t)(c * 8 + r7s) * SEQ + csw * 8, &Vs[0][c * 512]);
        }
        __syncthreads();

        #pragma unroll 1
        for (int it = 0; it <= Je; ++it) {
            const int k0 = it * 64;
            const int cur = it & 1;
            if (it < Je) {      // prefetch next tile into the other buffer
                #pragma unroll
                for (int i = 0; i < 2; ++i) {
                    const int c = wv * 2 + i;
                    GLL(Kb + (size_t)(k0 + 64 + c * 8 + r7s) * DH + csw * 8,
                        &Ks[cur ^ 1][c * 512]);
                    GLL(Vb + (size_t)(c * 8 + r7s) * SEQ + k0 + 64 + csw * 8,
                        &Vs[cur ^ 1][c * 512]);
                }
            }
            const ushort* KsC = Ks[cur];
            const ushort* VsC = Vs[cur];
            const bool diag = (it == Je);

            f32x4 sacc[4];
            #pragma unroll
            for (int nt = 0; nt < 4; ++nt) sacc[nt] = (f32x4){0.f, 0.f, 0.f, 0.f};
            #pragma unroll
            for (int nt = 0; nt < 4; ++nt) {
                if (!diag || (k0 + nt * 16 <= qmax)) {
                    const int row = nt * 16 + frow, r7 = row & 7;
                    #pragma unroll
                    for (int ks = 0; ks < 2; ++ks) {
                        short8 kf = *(const short8*)
                            &KsC[(row >> 3) * 512 + r7 * 64 + (((ks * 4 + fq) ^ r7) * 8)];
                        sacc[nt] = __builtin_amdgcn_mfma_f32_16x16x32_bf16(kf, qf[ks],
                                                                          sacc[nt], 0, 0, 0);
                    }
                }
            }
            // ---- softmax + PV in two 32-key passes ----
            #pragma unroll
            for (int kc = 0; kc < 2; ++kc) {
                if (!diag || (k0 + kc * 32 <= qmax)) {
                    #pragma unroll
                    for (int ntl = 0; ntl < 2; ++ntl) {
                        const int nt = kc * 2 + ntl;
                        uint2 dw; dw.x = 0u; dw.y = 0u;
                        if (!diag || (k0 + nt * 16 <= qmax)) {
                            float pp[4];
                            #pragma unroll
                            for (int r = 0; r < 4; ++r) {
                                const float e = EXP2F(sacc[nt][r]);
                                pp[r] = (!diag || (k0 + nt * 16 + fq * 4 + r <= qrow))
                                            ? e : 0.f;
                            }
                            dw.x = __builtin_amdgcn_perm(__float_as_uint(pp[1]),
                                                         __float_as_uint(pp[0]),
                                                         0x07060302u);
                            dw.y = __builtin_amdgcn_perm(__float_as_uint(pp[3]),
                                                         __float_as_uint(pp[2]),
                                                         0x07060302u);
                        }
                        *(uint2*)&plds[wv][frow * PSTR2 + ntl * 16 + fq * 4] = dw;
                    }
                    asm volatile("s_waitcnt lgkmcnt(0)" ::: "memory");
                    short8 pf = *(const short8*)&plds[wv][frow * PSTR2 + fq * 8];
                    lacc = __builtin_amdgcn_mfma_f32_16x16x32_bf16(ones, pf, lacc, 0, 0, 0);
                    #pragma unroll
                    for (int t = 0; t < 4; ++t) {
                        const int row = t * 16 + frow, r7 = row & 7;
                        short8 vf = *(const short8*)
                            &VsC[(row >> 3) * 512 + r7 * 64 + (((kc * 4 + fq) ^ r7) * 8)];
                        o[t] = __builtin_amdgcn_mfma_f32_16x16x32_bf16(vf, pf, o[t], 0, 0, 0);
                    }
                }
            }
            __syncthreads();   // joins readers of buf[cur] + drains prefetch
        }
        // ---- epilogue: O^T row=dh=t*16+fq*4+r, col=q=frow ----
        const float inv = 1.0f / lacc[0];
        ushort* cp = ctx + (size_t)(bb * SEQ + qrow) * DMODEL + h * DH;
        #pragma unroll
        for (int t = 0; t < 4; ++t) {
            ushort4v ov;
            #pragma unroll
            for (int r = 0; r < 4; ++r) ov[r] = f2bf(o[t][r] * inv);
            *(ushort4v*)&cp[t * 16 + fq * 4] = ov;
        }
    }
}

extern "C" void kernel_launch(void* const* d_in, const int* in_sizes, int n_in,
                              void* d_out, int out_size, void* d_ws, size_t ws_size,
                              hipStream_t stream) {
    const float* x  = (const float*)d_in[0];
    const float* wq = (const float*)d_in[1];
    const float* bq = (const float*)d_in[2];
    const float* wk = (const float*)d_in[3];
    const float* bk = (const float*)d_in[4];
    const float* wvp = (const float*)d_in[5];
    const float* bv = (const float*)d_in[6];
    const float* wo = (const float*)d_in[7];
    const float* bo = (const float*)d_in[8];
    float* out = (float*)d_out;
    ushort* ws = (ushort*)d_ws;

    const size_t QSZ = (size_t)BATCH * NH * SEQ * DH;  // 8388608 elems
    ushort* xbf   = ws;
    ushort* qws   = ws + QSZ;
    ushort* kws   = ws + 2 * QSZ;
    ushort* vtws  = ws + 3 * QSZ;
    ushort* ctxws = ws + 4 * QSZ;
    ushort* wtqkv = ws + 5 * QSZ;                      // [3072][1024] bf16
    ushort* wto   = wtqkv + 3 * (size_t)DMODEL * DMODEL;

    dim3 tb(256);
    prep<<<dim3(16, 16, 5), tb, 0, stream>>>(
        x, wq, wk, wvp, wo, xbf,
        wtqkv, wtqkv + (size_t)DMODEL * DMODEL,
        wtqkv + 2 * (size_t)DMODEL * DMODEL, wto);

    gemm_bt<0><<<dim3(24, 64), tb, 0, stream>>>(xbf, wtqkv, bq, bk, bv,
                                                qws, kws, vtws);
    flash_attn<<<dim3(1024), tb, 0, stream>>>(qws, kws, vtws, ctxws);
    gemm_bt<1><<<dim3(8, 64), tb, 0, stream>>>(ctxws, wto, bo, nullptr, nullptr,
                                               out, nullptr, nullptr);
}